// Round 3
// baseline (148.716 us; speedup 1.0000x reference)
//
#include <hip/hip_runtime.h>
#include <math.h>

namespace {

constexpr int kS = 26;
constexpr int kA = 5;
constexpr int kP = kS * kS * kA;        // 3380
constexpr int kM = 30;
constexpr int kB = 128;
constexpr float kCW = 16.0f;            // IM / S = 416 / 26
constexpr int kThreads = 1024;
constexpr int kWaves = kThreads / 64;   // 16
constexpr int kD = 25;                  // 5 + C channels
constexpr int kElems = kP * kD;         // 84500 floats per batch (16B-aligned per batch)

// P split across 2 blocks per batch; both chunk element counts divisible by 4
// so the float4 sweep stays 16B-aligned (batch base is 84500*4B, %16 == 0).
constexpr int kPsplit = 1692;           // chunk0: [0,1692)=42300 fl; chunk1: [1692,3380)=42200 fl
constexpr int kPChunkMax = kPsplit;     // >= 1688
constexpr int kMaskWC = (kPChunkMax + 31) / 32;  // 53 words covers both chunks

// ws layout (floats), blk in [0,256):
//   [blk*64 + 0]        obj_term partial
//   [blk*64 + 1]        noobj partial (c2_chunk - obj_c2_chunk)
//   [blk*64 + 2 + m]    best iou for GT m in this chunk (-inf if m invalid)
//   [blk*64 + 32 + m]   best GLOBAL p index (bitcast int) for GT m

__device__ __forceinline__ float sig(float x) { return 1.0f / (1.0f + expf(-x)); }

__global__ __launch_bounds__(kThreads) void loss_main(
    const float* __restrict__ pred,
    const float* __restrict__ targ,
    const float* __restrict__ anch,
    float* __restrict__ ws) {
  __shared__ float4 sbox[kPChunkMax];    // decoded (bx,by,bw,bh) for this chunk, ~27 KB
  __shared__ unsigned int sobj[kMaskWC]; // obj bitmask over chunk (relative p)
  __shared__ float t_raw[kM * 5];
  __shared__ float g_x1[kM], g_x2[kM], g_y1[kM], g_y2[kM], g_area[kM];
  __shared__ int s_valid[kM];
  __shared__ float s_best[kM];
  __shared__ int s_idx[kM];
  __shared__ float s_anc[2 * kA];
  __shared__ float red[kWaves][2];

  const int blk = blockIdx.x;
  const int b = blk >> 1;
  const int half = blk & 1;
  const int p0 = half ? kPsplit : 0;
  const int chunkN = half ? (kP - kPsplit) : kPsplit;   // 1688 or 1692
  const int tid = threadIdx.x;
  const int lane = tid & 63;
  const int wid = tid >> 6;

  if (tid < 2 * kA) s_anc[tid] = anch[tid];
  if (tid < kM * 5) t_raw[tid] = targ[b * (kM * 5) + tid];
  for (int i = tid; i < kMaskWC; i += kThreads) sobj[i] = 0u;
  __syncthreads();

  if (tid < kM) {
    const float t0 = t_raw[tid * 5 + 0];
    const float t1 = t_raw[tid * 5 + 1];
    const float t2 = t_raw[tid * 5 + 2];
    const float t3 = t_raw[tid * 5 + 3];
    const float t4 = t_raw[tid * 5 + 4];
    const float gxc = t0 + t2 * 0.5f;   // t0 + t2/2
    const float gyc = t1 + t3 * 0.5f;
    const float gw = t2 - t0;           // faithful to source
    const float gh = t3 * t1;           // faithful to source
    g_x1[tid] = gxc - gw * 0.5f;
    g_x2[tid] = gxc + gw * 0.5f;
    g_y1[tid] = gyc - gh * 0.5f;
    g_y2[tid] = gyc + gh * 0.5f;
    g_area[tid] = gw * gh;
    s_valid[tid] = (t4 == 1.0f) ? 1 : 0;
    s_best[tid] = -INFINITY;            // invalid m stay -inf; tail kernel ignores them
    s_idx[tid] = 0;
  }
  // g_* / s_valid consumed only after the next __syncthreads (post phase 1).

  // ---- phase 1: coalesced float4 sweep of this chunk's slab; decode the 5 useful
  //      channels into LDS; accumulate chunk's sum(conf^2) ----
  float c2_all = 0.0f;
  const float4* pv = reinterpret_cast<const float4*>(pred + (size_t)b * kElems);
  const int j0 = (p0 * kD) / 4;
  const int j1 = ((p0 + chunkN) * kD) / 4;
  for (int j = j0 + tid; j < j1; j += kThreads) {
    const float4 v = pv[j];
    int e = 4 * j;                      // absolute element index within batch
    int p = e / kD;
    int c = e - p * kD;
    const float vals[4] = {v.x, v.y, v.z, v.w};
#pragma unroll
    for (int k = 0; k < 4; ++k) {
      if (c < 5) {
        const float s = sig(vals[k]);
        float* bx = reinterpret_cast<float*>(&sbox[p - p0]);
        if (c == 0) {
          const int gx = (p / kA) % kS;
          bx[0] = (s + (float)gx) * kCW;
        } else if (c == 1) {
          const int gy = p / (kA * kS);
          bx[1] = (s + (float)gy) * kCW;
        } else if (c == 2) {
          bx[2] = expf(s * 0.5f) * s_anc[2 * (p % kA) + 0] * kCW;
        } else if (c == 3) {
          bx[3] = expf(s * 0.5f) * s_anc[2 * (p % kA) + 1] * kCW;
        } else {  // c == 4
          c2_all += s * s;
        }
      }
      if (++c == kD) { c = 0; ++p; }
    }
  }
  __syncthreads();

  // ---- phase 2: per-valid-GT argmax over this chunk (first-index tie-break) + obj mask ----
  for (int m = wid; m < kM; m += kWaves) {
    if (!s_valid[m]) continue;  // wave-uniform branch
    const float gx1 = g_x1[m], gx2 = g_x2[m];
    const float gy1 = g_y1[m], gy2 = g_y2[m];
    const float ga = g_area[m];
    float best = -INFINITY;
    int bi = p0;
    for (int pr = lane; pr < chunkN; pr += 64) {
      const float4 box = sbox[pr];
      const float hw = box.z * 0.5f, hh = box.w * 0.5f;
      const float px1 = box.x - hw, px2 = box.x + hw;
      const float py1 = box.y - hh, py2 = box.y + hh;
      float dx = fminf(gx2, px2) - fmaxf(gx1, px1);
      float dy = fminf(gy2, py2) - fmaxf(gy1, py1);
      dx = fmaxf(dx, 0.0f);
      dy = fmaxf(dy, 0.0f);
      const float inter = dx * dy;
      const float uni = ga + box.z * box.w - inter;
      const float iou = inter / (uni + 1e-9f);
      if (iou > 0.6f) atomicOr(&sobj[pr >> 5], 1u << (pr & 31));
      if (iou > best) { best = iou; bi = p0 + pr; }  // strict > keeps first occurrence
    }
#pragma unroll
    for (int off = 32; off > 0; off >>= 1) {
      const float ob = __shfl_down(best, off);
      const int oi = __shfl_down(bi, off);
      if (ob > best || (ob == best && oi < bi)) { best = ob; bi = oi; }
    }
    if (lane == 0) { s_best[m] = best; s_idx[m] = bi; }
  }
  __syncthreads();

  // ---- phase 3: sparse conf-obj terms over this chunk's mask ----
  float obj_term = 0.0f, obj_c2 = 0.0f;
  for (int pr = tid; pr < chunkN; pr += kThreads) {
    if ((sobj[pr >> 5] >> (pr & 31)) & 1u) {
      const float c = sig(pred[((size_t)b * kP + p0 + pr) * kD + 4]);
      const float d = c - 1.0f;
      obj_term += d * d;
      obj_c2 += c * c;
    }
  }

  // ---- block reduce: [obj_term, noobj_partial] ----
  float v0 = obj_term;
  float v1 = c2_all - obj_c2;
#pragma unroll
  for (int off = 32; off > 0; off >>= 1) {
    v0 += __shfl_down(v0, off);
    v1 += __shfl_down(v1, off);
  }
  if (lane == 0) { red[wid][0] = v0; red[wid][1] = v1; }
  __syncthreads();
  if (tid == 0) {
    float a0 = 0.f, a1 = 0.f;
    for (int w = 0; w < kWaves; ++w) { a0 += red[w][0]; a1 += red[w][1]; }
    ws[blk * 64 + 0] = a0;
    ws[blk * 64 + 1] = a1;
  }
  if (tid < kM) {
    ws[blk * 64 + 2 + tid] = s_best[tid];
    ws[blk * 64 + 32 + tid] = __int_as_float(s_idx[tid]);
  }
}

// Single-block tail: per-batch chunk merge + duplicate rule + loc loss + final
// reduction + scaling. 16 waves; wave w owns batches w*8 .. w*8+7 (all wave-local,
// no barriers except the one LDS reduction stage).
__global__ __launch_bounds__(kThreads) void loss_tail(
    const float* __restrict__ pred,
    const float* __restrict__ targ,
    const float* __restrict__ anch,
    const float* __restrict__ ws,
    float* __restrict__ out) {
  __shared__ float red[kWaves][3];
  const int tid = threadIdx.x;
  const int lane = tid & 63;
  const int wv = tid >> 6;

  float obj = 0.0f, noobj = 0.0f, loc = 0.0f;
  for (int i = 0; i < kB / kWaves; ++i) {   // 8 batches per wave
    const int b = wv * (kB / kWaves) + i;
    if (lane == 0) {
      obj += ws[(2 * b) * 64 + 0] + ws[(2 * b + 1) * 64 + 0];
      noobj += ws[(2 * b) * 64 + 1] + ws[(2 * b + 1) * 64 + 1];
    }
    int idx = -1;
    int valid = 0;
    if (lane < kM) {
      const float t4 = targ[b * (kM * 5) + lane * 5 + 4];
      valid = (t4 == 1.0f) ? 1 : 0;
      const float b0 = ws[(2 * b) * 64 + 2 + lane];
      const float b1 = ws[(2 * b + 1) * 64 + 2 + lane];
      const int i0 = __float_as_int(ws[(2 * b) * 64 + 32 + lane]);
      const int i1 = __float_as_int(ws[(2 * b + 1) * 64 + 32 + lane]);
      // ties pick the lower global index; chunk0 indices are all lower -> b1 must
      // strictly exceed b0 to win. Matches single-pass first-index argmax.
      idx = (b1 > b0) ? i1 : i0;
    }
    // duplicate-index rule: LAST valid m wins -> m is dead if any valid m2>m shares idx.
    bool live = (valid != 0);
    for (int d = 1; d < kM; ++d) {
      const int oidx = __shfl_down(idx, d);
      const int ovalid = __shfl_down(valid, d);
      if (lane + d < kM && ovalid && oidx == idx) live = false;
    }
    if (valid && live) {
      const int m = lane;
      const float t0 = targ[b * (kM * 5) + m * 5 + 0];
      const float t1 = targ[b * (kM * 5) + m * 5 + 1];
      const float t2 = targ[b * (kM * 5) + m * 5 + 2];
      const float t3 = targ[b * (kM * 5) + m * 5 + 3];
      const float gxc = t0 + t2 * 0.5f;
      const float gyc = t1 + t3 * 0.5f;
      const int ra = idx % kA;
      const int rw = (idx / kA) % kS;
      const int rh = idx / (kA * kS);
      const float tx = (gxc - (float)rw * kCW) / kCW;
      const float ty = (gyc - (float)rh * kCW) / kCW;
      const float tw = logf((t2 / kCW) / anch[2 * ra + 0]);
      const float th = logf((t3 / kCW) / anch[2 * ra + 1]);
      const float* pp = pred + ((size_t)b * kP + idx) * kD;
      const float d0 = sig(pp[0]) - tx;
      const float d1 = sig(pp[1]) - ty;
      const float d2 = sig(pp[2]) * 0.5f - tw;
      const float d3 = sig(pp[3]) * 0.5f - th;
      loc += d0 * d0 + d1 * d1 + d2 * d2 + d3 * d3;
    }
  }

#pragma unroll
  for (int off = 32; off > 0; off >>= 1) {
    obj += __shfl_down(obj, off);
    noobj += __shfl_down(noobj, off);
    loc += __shfl_down(loc, off);
  }
  if (lane == 0) { red[wv][0] = obj; red[wv][1] = noobj; red[wv][2] = loc; }
  __syncthreads();
  if (tid == 0) {
    float a0 = 0.f, a1 = 0.f, a2 = 0.f;
    for (int w = 0; w < kWaves; ++w) { a0 += red[w][0]; a1 += red[w][1]; a2 += red[w][2]; }
    const float loss_conf = (a0 + 0.5f * a1) / (float)kB;
    const float loss_loc = 5.0f * a2 / (float)kB;
    out[0] = loss_loc + loss_conf;
    out[1] = loss_loc;
    out[2] = loss_conf;
  }
}

}  // namespace

extern "C" void kernel_launch(void* const* d_in, const int* in_sizes, int n_in,
                              void* d_out, int out_size, void* d_ws, size_t ws_size,
                              hipStream_t stream) {
  const float* pred = (const float*)d_in[0];
  const float* targ = (const float*)d_in[1];
  const float* anch = (const float*)d_in[2];
  float* out = (float*)d_out;
  float* ws = (float*)d_ws;  // needs 256*64 floats = 64 KB
  loss_main<<<2 * kB, kThreads, 0, stream>>>(pred, targ, anch, ws);
  loss_tail<<<1, kThreads, 0, stream>>>(pred, targ, anch, ws, out);
}

// Round 5
// 109.295 us; speedup vs baseline: 1.3607x; 1.3607x over previous
//
#include <hip/hip_runtime.h>
#include <math.h>

namespace {

constexpr int kS = 26;
constexpr int kA = 5;
constexpr int kP = kS * kS * kA;        // 3380
constexpr int kM = 30;
constexpr int kB = 128;
constexpr float kCW = 16.0f;            // IM / S = 416 / 26
constexpr int kThreads = 1024;
constexpr int kWaves = kThreads / 64;   // 16
constexpr int kD = 25;                  // 5 + C channels
constexpr int kElems = kP * kD;         // 84500 floats per batch

// 4 chunks per batch; box_count*25 is divisible by 4 for each chunk boundary
// (848*25=21200), keeping the float4 sweep 16B-aligned (batch base % 16 == 0).
constexpr int kChunks = 4;
constexpr int kPC = 848;                // chunks 0..2; last = 3380 - 2544 = 836
constexpr int kPCMax = kPC;
constexpr int kMaskWC = (kPCMax + 31) / 32;  // 27

// ws layout (floats), chunk blocks blk in [0,512):
//   [blk*64 + 0]        obj_term partial
//   [blk*64 + 1]        noobj partial (c2_chunk - obj_c2_chunk)
//   [blk*64 + 2 + m]    best iou for GT m in this chunk (-inf if m invalid)
//   [blk*64 + 32 + m]   best GLOBAL p index (bitcast int) for GT m
// then per-batch combined results + completion counter:
constexpr int kWsTail = 512 * 64;       // 32768 floats
constexpr int kCtrOff = kWsTail + 3 * kB;  // int counter lives here

__device__ __forceinline__ float sig(float x) { return 1.0f / (1.0f + expf(-x)); }

__global__ __launch_bounds__(kThreads) void loss_main(
    const float* __restrict__ pred,
    const float* __restrict__ targ,
    const float* __restrict__ anch,
    float* __restrict__ ws) {
  __shared__ float s_ch[kPCMax * 5];     // raw channels 0..4 per box, 17 KB
  __shared__ float4 sbox[kPCMax];        // decoded (bx,by,bw,bh), 13.6 KB
  __shared__ unsigned int sobj[kMaskWC]; // obj bitmask over chunk (relative p)
  __shared__ float t_raw[kM * 5];
  __shared__ float g_x1[kM], g_x2[kM], g_y1[kM], g_y2[kM], g_area[kM];
  __shared__ int s_valid[kM];
  __shared__ float s_best[kM];
  __shared__ int s_idx[kM];
  __shared__ float s_anc[2 * kA];
  __shared__ float red[kWaves][2];

  const int blk = blockIdx.x;
  const int b = blk >> 2;
  const int q = blk & 3;
  const int p0 = q * kPC;
  const int chunkN = (q == 3) ? (kP - 3 * kPC) : kPC;   // 836 or 848
  const int tid = threadIdx.x;
  const int lane = tid & 63;
  const int wid = tid >> 6;

  if (blk == 0 && tid == 0) {
    reinterpret_cast<int*>(ws)[kCtrOff] = 0;  // reset tail completion counter
  }
  if (tid < 2 * kA) s_anc[tid] = anch[tid];
  if (tid < kM * 5) t_raw[tid] = targ[b * (kM * 5) + tid];
  for (int i = tid; i < kMaskWC; i += kThreads) sobj[i] = 0u;
  __syncthreads();

  if (tid < kM) {
    const float t0 = t_raw[tid * 5 + 0];
    const float t1 = t_raw[tid * 5 + 1];
    const float t2 = t_raw[tid * 5 + 2];
    const float t3 = t_raw[tid * 5 + 3];
    const float t4 = t_raw[tid * 5 + 4];
    const float gxc = t0 + t2 * 0.5f;   // t0 + t2/2
    const float gyc = t1 + t3 * 0.5f;
    const float gw = t2 - t0;           // faithful to source
    const float gh = t3 * t1;           // faithful to source
    g_x1[tid] = gxc - gw * 0.5f;
    g_x2[tid] = gxc + gw * 0.5f;
    g_y1[tid] = gyc - gh * 0.5f;
    g_y2[tid] = gyc + gh * 0.5f;
    g_area[tid] = gw * gh;
    s_valid[tid] = (t4 == 1.0f) ? 1 : 0;
    s_best[tid] = -INFINITY;            // invalid m stay -inf; tail ignores them
    s_idx[tid] = 0;
  }
  // g_* / s_valid consumed only after the phase-B barrier below.

  // ---- pass A: coalesced float4 sweep; stash raw channels c<5 to LDS.
  //      One predicated 4B store per element, arithmetic address, no branch chain.
  const float4* pv = reinterpret_cast<const float4*>(pred + (size_t)b * kElems);
  const int j0 = (p0 * kD) / 4;
  const int j1 = ((p0 + chunkN) * kD) / 4;
  for (int j = j0 + tid; j < j1; j += kThreads) {
    const float4 v = pv[j];
    int e = 4 * j - p0 * kD;            // element index relative to chunk
    int p = e / kD;
    int c = e - p * kD;
    const float vals[4] = {v.x, v.y, v.z, v.w};
#pragma unroll
    for (int k = 0; k < 4; ++k) {
      if (c < 5) s_ch[p * 5 + c] = vals[k];
      if (++c == kD) { c = 0; ++p; }
    }
  }
  __syncthreads();

  // ---- pass B: uniform per-box decode (no divergence); accumulate sum(conf^2) ----
  float c2_all = 0.0f;
  for (int pr = tid; pr < chunkN; pr += kThreads) {
    const float r0 = s_ch[pr * 5 + 0];
    const float r1 = s_ch[pr * 5 + 1];
    const float r2 = s_ch[pr * 5 + 2];
    const float r3 = s_ch[pr * 5 + 3];
    const float r4 = s_ch[pr * 5 + 4];
    const float cc = sig(r4);
    c2_all += cc * cc;
    const int pg = p0 + pr;
    const int a = pg % kA;
    const int gx = (pg / kA) % kS;
    const int gy = pg / (kA * kS);
    float4 box;
    box.x = (sig(r0) + (float)gx) * kCW;
    box.y = (sig(r1) + (float)gy) * kCW;
    box.z = expf(sig(r2) * 0.5f) * s_anc[2 * a + 0] * kCW;
    box.w = expf(sig(r3) * 0.5f) * s_anc[2 * a + 1] * kCW;
    sbox[pr] = box;
  }
  __syncthreads();

  // ---- phase 2: per-valid-GT argmax over this chunk (first-index tie-break) + obj mask ----
  for (int m = wid; m < kM; m += kWaves) {
    if (!s_valid[m]) continue;  // wave-uniform branch
    const float gx1 = g_x1[m], gx2 = g_x2[m];
    const float gy1 = g_y1[m], gy2 = g_y2[m];
    const float ga = g_area[m];
    float best = -INFINITY;
    int bi = p0;
    for (int pr = lane; pr < chunkN; pr += 64) {
      const float4 box = sbox[pr];
      const float hw = box.z * 0.5f, hh = box.w * 0.5f;
      const float px1 = box.x - hw, px2 = box.x + hw;
      const float py1 = box.y - hh, py2 = box.y + hh;
      float dx = fminf(gx2, px2) - fmaxf(gx1, px1);
      float dy = fminf(gy2, py2) - fmaxf(gy1, py1);
      dx = fmaxf(dx, 0.0f);
      dy = fmaxf(dy, 0.0f);
      const float inter = dx * dy;
      const float uni = ga + box.z * box.w - inter;
      const float iou = inter / (uni + 1e-9f);
      if (iou > 0.6f) atomicOr(&sobj[pr >> 5], 1u << (pr & 31));
      if (iou > best) { best = iou; bi = p0 + pr; }  // strict > keeps first occurrence
    }
#pragma unroll
    for (int off = 32; off > 0; off >>= 1) {
      const float ob = __shfl_down(best, off);
      const int oi = __shfl_down(bi, off);
      if (ob > best || (ob == best && oi < bi)) { best = ob; bi = oi; }
    }
    if (lane == 0) { s_best[m] = best; s_idx[m] = bi; }
  }
  __syncthreads();

  // ---- phase 3: sparse conf-obj terms from LDS raw conf ----
  float obj_term = 0.0f, obj_c2 = 0.0f;
  for (int pr = tid; pr < chunkN; pr += kThreads) {
    if ((sobj[pr >> 5] >> (pr & 31)) & 1u) {
      const float c = sig(s_ch[pr * 5 + 4]);
      const float d = c - 1.0f;
      obj_term += d * d;
      obj_c2 += c * c;
    }
  }

  // ---- block reduce: [obj_term, noobj_partial] ----
  float v0 = obj_term;
  float v1 = c2_all - obj_c2;
#pragma unroll
  for (int off = 32; off > 0; off >>= 1) {
    v0 += __shfl_down(v0, off);
    v1 += __shfl_down(v1, off);
  }
  if (lane == 0) { red[wid][0] = v0; red[wid][1] = v1; }
  __syncthreads();
  if (tid == 0) {
    float a0 = 0.f, a1 = 0.f;
    for (int w = 0; w < kWaves; ++w) { a0 += red[w][0]; a1 += red[w][1]; }
    ws[blk * 64 + 0] = a0;
    ws[blk * 64 + 1] = a1;
  }
  if (tid < kM) {
    ws[blk * 64 + 2 + tid] = s_best[tid];
    ws[blk * 64 + 32 + tid] = __int_as_float(s_idx[tid]);
  }
}

// One block per batch (64 threads): merge 4 chunk argmaxes, duplicate rule,
// loc loss; last block (atomic election) does the deterministic final reduce.
__global__ __launch_bounds__(64) void loss_tail(
    const float* __restrict__ pred,
    const float* __restrict__ targ,
    const float* __restrict__ anch,
    float* __restrict__ ws,
    float* __restrict__ out) {
  const int b = blockIdx.x;
  const int lane = threadIdx.x;

  float obj = 0.0f, noobj = 0.0f, loc = 0.0f;
  if (lane == 0) {
#pragma unroll
    for (int q = 0; q < kChunks; ++q) {
      obj += ws[(4 * b + q) * 64 + 0];
      noobj += ws[(4 * b + q) * 64 + 1];
    }
  }
  int idx = -1;
  int valid = 0;
  if (lane < kM) {
    const float t4 = targ[b * (kM * 5) + lane * 5 + 4];
    valid = (t4 == 1.0f) ? 1 : 0;
    float best = ws[(4 * b) * 64 + 2 + lane];
    idx = __float_as_int(ws[(4 * b) * 64 + 32 + lane]);
#pragma unroll
    for (int q = 1; q < kChunks; ++q) {
      const float bq = ws[(4 * b + q) * 64 + 2 + lane];
      const int iq = __float_as_int(ws[(4 * b + q) * 64 + 32 + lane]);
      // strict >: ascending chunks have ascending indices, so ties keep the
      // lower global index — matches single-pass first-index argmax.
      if (bq > best) { best = bq; idx = iq; }
    }
  }
  // duplicate-index rule: LAST valid m wins -> m dead if any valid m2>m shares idx.
  bool live = (valid != 0);
  for (int d = 1; d < kM; ++d) {
    const int oidx = __shfl_down(idx, d);
    const int ovalid = __shfl_down(valid, d);
    if (lane + d < kM && ovalid && oidx == idx) live = false;
  }
  if (valid && live) {
    const int m = lane;
    const float t0 = targ[b * (kM * 5) + m * 5 + 0];
    const float t1 = targ[b * (kM * 5) + m * 5 + 1];
    const float t2 = targ[b * (kM * 5) + m * 5 + 2];
    const float t3 = targ[b * (kM * 5) + m * 5 + 3];
    const float gxc = t0 + t2 * 0.5f;
    const float gyc = t1 + t3 * 0.5f;
    const int ra = idx % kA;
    const int rw = (idx / kA) % kS;
    const int rh = idx / (kA * kS);
    const float tx = (gxc - (float)rw * kCW) / kCW;
    const float ty = (gyc - (float)rh * kCW) / kCW;
    const float tw = logf((t2 / kCW) / anch[2 * ra + 0]);
    const float th = logf((t3 / kCW) / anch[2 * ra + 1]);
    const float* pp = pred + ((size_t)b * kP + idx) * kD;
    const float d0 = sig(pp[0]) - tx;
    const float d1 = sig(pp[1]) - ty;
    const float d2 = sig(pp[2]) * 0.5f - tw;
    const float d3 = sig(pp[3]) * 0.5f - th;
    loc = d0 * d0 + d1 * d1 + d2 * d2 + d3 * d3;
  }

#pragma unroll
  for (int off = 32; off > 0; off >>= 1) {
    obj += __shfl_down(obj, off);
    noobj += __shfl_down(noobj, off);
    loc += __shfl_down(loc, off);
  }
  if (lane == 0) {
    __hip_atomic_store(&ws[kWsTail + b * 3 + 0], obj, __ATOMIC_RELEASE,
                       __HIP_MEMORY_SCOPE_AGENT);
    __hip_atomic_store(&ws[kWsTail + b * 3 + 1], noobj, __ATOMIC_RELEASE,
                       __HIP_MEMORY_SCOPE_AGENT);
    __hip_atomic_store(&ws[kWsTail + b * 3 + 2], loc, __ATOMIC_RELEASE,
                       __HIP_MEMORY_SCOPE_AGENT);
  }
  __threadfence();

  int old = 0;
  if (lane == 0) old = atomicAdd(reinterpret_cast<int*>(ws) + kCtrOff, 1);
  old = __shfl(old, 0);
  if (old == kB - 1) {
    __threadfence();
    // deterministic fixed-tree reduce: lane l owns batches l and l+64
    float a0 = 0.f, a1 = 0.f, a2 = 0.f;
#pragma unroll
    for (int h = 0; h < 2; ++h) {
      const int bb = lane + 64 * h;
      a0 += __hip_atomic_load(&ws[kWsTail + bb * 3 + 0], __ATOMIC_ACQUIRE,
                              __HIP_MEMORY_SCOPE_AGENT);
      a1 += __hip_atomic_load(&ws[kWsTail + bb * 3 + 1], __ATOMIC_ACQUIRE,
                              __HIP_MEMORY_SCOPE_AGENT);
      a2 += __hip_atomic_load(&ws[kWsTail + bb * 3 + 2], __ATOMIC_ACQUIRE,
                              __HIP_MEMORY_SCOPE_AGENT);
    }
#pragma unroll
    for (int off = 32; off > 0; off >>= 1) {
      a0 += __shfl_down(a0, off);
      a1 += __shfl_down(a1, off);
      a2 += __shfl_down(a2, off);
    }
    if (lane == 0) {
      const float loss_conf = (a0 + 0.5f * a1) / (float)kB;
      const float loss_loc = 5.0f * a2 / (float)kB;
      out[0] = loss_loc + loss_conf;
      out[1] = loss_loc;
      out[2] = loss_conf;
    }
  }
}

}  // namespace

extern "C" void kernel_launch(void* const* d_in, const int* in_sizes, int n_in,
                              void* d_out, int out_size, void* d_ws, size_t ws_size,
                              hipStream_t stream) {
  const float* pred = (const float*)d_in[0];
  const float* targ = (const float*)d_in[1];
  const float* anch = (const float*)d_in[2];
  float* out = (float*)d_out;
  float* ws = (float*)d_ws;  // needs (512*64 + 384 + 1) floats ~= 130 KB
  loss_main<<<kChunks * kB, kThreads, 0, stream>>>(pred, targ, anch, ws);
  loss_tail<<<kB, 64, 0, stream>>>(pred, targ, anch, ws, out);
}